// Round 5
// baseline (1903.927 us; speedup 1.0000x reference)
//
#include <hip/hip_runtime.h>
#include <hip/hip_bf16.h>

namespace {

constexpr int kB = 32;
constexpr int kT = 512;
constexpr int kH = 512;
constexpr int kE = 256;
constexpr int kL = 64;
constexpr int kNC = 7 * kH;       // 3584 gate columns
constexpr int kOutRow = 5 * kH;   // 2560
constexpr int kBH = kB * kH;      // 16384 elements per parity slot

typedef float f32x4 __attribute__((ext_vector_type(4)));
typedef short s16x8 __attribute__((ext_vector_type(8)));
typedef __bf16 bf16x8 __attribute__((ext_vector_type(8)));
typedef unsigned int u32x4 __attribute__((ext_vector_type(4)));
typedef unsigned int u32x2 __attribute__((ext_vector_type(2)));

__device__ __forceinline__ unsigned short f2bf(float f) {
  __hip_bfloat16 h = __float2bfloat16(f);
  return __builtin_bit_cast(unsigned short, h);
}

__device__ __forceinline__ float bf2f(unsigned short u) {
  return __builtin_bit_cast(float, (unsigned int)u << 16);
}

// libm versions (setup only)
__device__ __forceinline__ float sigmoid_f(float x) {
  return 1.0f / (1.0f + expf(-x));
}
__device__ __forceinline__ float softplus_f(float x) {
  return fmaxf(x, 0.0f) + log1pf(expf(-fabsf(x)));
}

// fast versions (hot kernel)
constexpr float kLog2e = 1.4426950408889634f;
constexpr float kLn2 = 0.6931471805599453f;
__device__ __forceinline__ float fexp2(float x) {
  return __builtin_amdgcn_exp2f(x);
}
__device__ __forceinline__ float frcp(float x) {
  return __builtin_amdgcn_rcpf(x);
}
__device__ __forceinline__ float fsigmoid(float x) {
  return frcp(1.0f + fexp2(-x * kLog2e));
}
__device__ __forceinline__ float ftanh(float x) {
  return 1.0f - 2.0f * frcp(1.0f + fexp2((2.0f * kLog2e) * x));
}
__device__ __forceinline__ float fsoftplus(float x) {
  return fmaxf(x, 0.0f) +
         kLn2 * __builtin_amdgcn_logf(1.0f + fexp2(-fabsf(x) * kLog2e));
}

__device__ __forceinline__ f32x4 mfma_bf16(s16x8 a, s16x8 b, f32x4 c) {
  return __builtin_amdgcn_mfma_f32_16x16x32_bf16(
      __builtin_bit_cast(bf16x8, a), __builtin_bit_cast(bf16x8, b), c, 0, 0, 0);
}

__device__ __forceinline__ void st_coh_x2(unsigned int* p, u32x2 v) {
  asm volatile("global_store_dwordx2 %0, %1, off sc0 sc1" :: "v"(p), "v"(v)
               : "memory");
}

__device__ __forceinline__ void unpack(const u32x4& x0, const u32x4& x1,
                                       s16x8& hi, s16x8& lo) {
#pragma unroll
  for (int e = 0; e < 4; ++e) {
    hi[e] = (short)(x0[e] & 0xffffu);
    hi[e + 4] = (short)(x1[e] & 0xffffu);
    lo[e] = (short)(x0[e] >> 16);
    lo[e + 4] = (short)(x1[e] >> 16);
  }
}

// ---------------------------------------------------------------------------
// Setup: emb_part [128][3584], lat_part(+bias) [32][3584], dt [32][512],
// init states -> out row 0, hdtag parity0 = {h0, tag 0}, parity1 poisoned.
// ---------------------------------------------------------------------------
__global__ void hawkes_setup(const float* __restrict__ ts,
                             const float* __restrict__ latent,
                             const float* __restrict__ emb,
                             const float* __restrict__ Wc,
                             const float* __restrict__ bc,
                             const float* __restrict__ Wi,
                             const float* __restrict__ bi,
                             float* __restrict__ out,
                             float* __restrict__ emb_part,
                             float* __restrict__ lat_part,
                             float* __restrict__ dt,
                             float* __restrict__ cd0,
                             float* __restrict__ cb0,
                             unsigned int* __restrict__ hdtag) {
  const int blk = blockIdx.x;
  const int tid = threadIdx.x;
  if (blk < 112) {
    __shared__ float es[16][kE];
    const int cgrp = blk / 14;
    const int col = (blk % 14) * 256 + tid;
    for (int i = tid; i < 16 * kE; i += 256)
      es[i / kE][i % kE] = emb[(cgrp * 16 + i / kE) * kE + (i % kE)];
    __syncthreads();
    float acc[16];
#pragma unroll
    for (int c = 0; c < 16; ++c) acc[c] = 0.0f;
    for (int e = 0; e < kE; ++e) {
      const float w = Wc[(size_t)e * kNC + col];
#pragma unroll
      for (int c = 0; c < 16; ++c) acc[c] = fmaf(es[c][e], w, acc[c]);
    }
#pragma unroll
    for (int c = 0; c < 16; ++c)
      emb_part[(size_t)(cgrp * 16 + c) * kNC + col] = acc[c];
  } else if (blk < 126) {
    __shared__ float ls[kB][kL];
    const int col = (blk - 112) * 256 + tid;
    for (int i = tid; i < kB * kL; i += 256) ls[i / kL][i % kL] = latent[i];
    __syncthreads();
    float acc[kB];
    const float bias = bc[col];
#pragma unroll
    for (int b = 0; b < kB; ++b) acc[b] = bias;
    for (int l = 0; l < kL; ++l) {
      const float w = Wc[(size_t)(kE + l) * kNC + col];
#pragma unroll
      for (int b = 0; b < kB; ++b) acc[b] = fmaf(ls[b][l], w, acc[b]);
    }
#pragma unroll
    for (int b = 0; b < kB; ++b) lat_part[(size_t)b * kNC + col] = acc[b];
  } else if (blk < 222) {
    const int tg = (blk - 126) * 256 + tid;
    for (int it = 0; it < 4; ++it) {
      const int item = tg + it * 24576;
      const int b = item / 3072;
      const int c6 = item % 3072;
      float a = bi[c6];
      for (int l = 0; l < kL; ++l)
        a = fmaf(latent[b * kL + l], Wi[(size_t)l * 3072 + c6], a);
      const int which = c6 >> 9;
      const int jl = c6 & 511;
      float* orow = out + (size_t)b * (kT + 1) * kOutRow;
      if (which == 0) {
        const float h = tanhf(a);
        orow[jl] = h;
        const unsigned int hh = f2bf(h);
        const unsigned int hl = f2bf(h - bf2f((unsigned short)hh));
        u32x2 v0 = {hh | (hl << 16), 0u};
        u32x2 v1 = {0u, 0xFFFFFFFFu};
        st_coh_x2(hdtag + (size_t)(b * kH + jl) * 2, v0);
        st_coh_x2(hdtag + (size_t)(kBH + b * kH + jl) * 2, v1);
      } else if (which == 1) {
        cd0[b * kH + jl] = tanhf(a);
      } else if (which == 2) {
        const float v = tanhf(a);
        orow[2 * kH + jl] = v;
        cb0[b * kH + jl] = v;
      } else if (which == 3) {
        orow[3 * kH + jl] = tanhf(a);
      } else if (which == 4) {
        orow[4 * kH + jl] = softplus_f(a);
      } else {
        orow[kH + jl] = sigmoid_f(a);
      }
    }
  } else {
    const int idx = (blk - 222) * 256 + tid;   // [0,16384)
    const int b = idx >> 9;
    const int t = idx & 511;
    dt[idx] = (t == 0) ? ts[b * kT] : ts[b * kT + t] - ts[b * kT + t - 1];
  }
}

// ---------------------------------------------------------------------------
// Sequential scan: 64 blocks = 2 batch-groups (16 batches, independent) x
// 32 hidden-tiles (16 units). 256 threads = 4 waves; wave w owns k-slice
// [w*128, w*128+128) for all 7 gates, weights persistent (bf16 hi/lo).
// M=16 MFMA rows = 16 real batches (no replication). Per step:
//   1) coop tagged load 16x512 h_d (coalesced, poll==load) -> LDS
//   2) sync; 84 MFMAs/wave; partials -> pl
//   3) sync; ALL 256 threads: reduce 4 partials, pointwise (b,j), publish.
// ---------------------------------------------------------------------------
__global__ __launch_bounds__(256, 1) void hawkes_seq(
    const int* __restrict__ marks, const float* __restrict__ Wc,
    float* __restrict__ out, const float* __restrict__ emb_part,
    const float* __restrict__ lat_part, const float* __restrict__ dt,
    const float* __restrict__ cd0, const float* __restrict__ cb0,
    unsigned int* __restrict__ hdtag) {
  const int blk = blockIdx.x;
  const int grp = blk >> 5;                // batch group 0..1
  const int jt = blk & 31;                 // hidden tile 0..31
  const int tid = threadIdx.x;             // 0..255
  const int wave = tid >> 6;               // k-slice 0..3
  const int lane = tid & 63;
  const int nl = lane & 15;                // A row (batch) / B col (unit)
  const int kg = lane >> 4;                // k-subgroup 0..3

  __shared__ __align__(16) unsigned int lds_a[16][516];  // 33,024 B
  __shared__ __align__(16) float pl[7][16][68];          // 30,464 B (pad 4)

  // --- persistent weight fragments: 7 gates x 4 ktiles, hi/lo split ---
  s16x8 whi[7][4], wlo[7][4];
  {
    const float* Wh = Wc + (size_t)(kE + kL) * kNC;
    const int colbase = jt * 16 + nl;
#pragma unroll
    for (int g = 0; g < 7; ++g) {
#pragma unroll
      for (int kt = 0; kt < 4; ++kt) {
        s16x8 hi, lo;
#pragma unroll
        for (int e = 0; e < 8; ++e) {
          const float w =
              Wh[(size_t)(wave * 128 + kt * 32 + kg * 8 + e) * kNC +
                 g * kH + colbase];
          const unsigned short h = f2bf(w);
          hi[e] = (short)h;
          lo[e] = (short)f2bf(w - bf2f(h));
        }
        whi[g][kt] = hi;
        wlo[g][kt] = lo;
      }
    }
  }

  // --- pointwise identity: thread (b_loc, j_loc), all 256 threads ---
  const int b_loc = tid >> 4;
  const int j_loc = tid & 15;
  const int b_glob = grp * 16 + b_loc;
  const int u_pw = jt * 16 + j_loc;
  float c_d = cd0[b_glob * kH + u_pw];
  float c_bar = cb0[b_glob * kH + u_pw];
  float dtv = dt[b_glob * kT + 0];
  float rb[7];
  {
    const int mk = marks[b_glob * kT + 0];
#pragma unroll
    for (int m = 0; m < 7; ++m)
      rb[m] = emb_part[(size_t)mk * kNC + m * kH + u_pw] +
              lat_part[(size_t)b_glob * kNC + m * kH + u_pw];
  }

  const size_t grp_byte = (size_t)grp * 16 * kH * 8;

  for (int s = 1; s <= kT; ++s) {
    // ---- 1) coop tagged load: 16 x dwordx4, coalesced, retry-all ----
    const unsigned int tg = (unsigned int)(s - 1);
    const char* pb = (const char*)hdtag +
                     (size_t)((s - 1) & 1) * (kBH * 8) + grp_byte +
                     (size_t)tid * 16 + 4096;
    u32x4 d0, d1, d2, d3, d4, d5, d6, d7, d8, d9, d10, d11, d12, d13, d14,
        d15;
    for (;;) {
      asm volatile(
          "global_load_dwordx4 %0, %16, off offset:-4096 sc0 sc1\n\t"
          "global_load_dwordx4 %1, %16, off sc0 sc1\n\t"
          "global_load_dwordx4 %2, %17, off offset:-4096 sc0 sc1\n\t"
          "global_load_dwordx4 %3, %17, off sc0 sc1\n\t"
          "global_load_dwordx4 %4, %18, off offset:-4096 sc0 sc1\n\t"
          "global_load_dwordx4 %5, %18, off sc0 sc1\n\t"
          "global_load_dwordx4 %6, %19, off offset:-4096 sc0 sc1\n\t"
          "global_load_dwordx4 %7, %19, off sc0 sc1\n\t"
          "global_load_dwordx4 %8, %20, off offset:-4096 sc0 sc1\n\t"
          "global_load_dwordx4 %9, %20, off sc0 sc1\n\t"
          "global_load_dwordx4 %10, %21, off offset:-4096 sc0 sc1\n\t"
          "global_load_dwordx4 %11, %21, off sc0 sc1\n\t"
          "global_load_dwordx4 %12, %22, off offset:-4096 sc0 sc1\n\t"
          "global_load_dwordx4 %13, %22, off sc0 sc1\n\t"
          "global_load_dwordx4 %14, %23, off offset:-4096 sc0 sc1\n\t"
          "global_load_dwordx4 %15, %23, off sc0 sc1\n\t"
          "s_waitcnt vmcnt(0)"
          : "=v"(d0), "=v"(d1), "=v"(d2), "=v"(d3), "=v"(d4), "=v"(d5),
            "=v"(d6), "=v"(d7), "=v"(d8), "=v"(d9), "=v"(d10), "=v"(d11),
            "=v"(d12), "=v"(d13), "=v"(d14), "=v"(d15)
          : "v"(pb), "v"(pb + 8192), "v"(pb + 16384), "v"(pb + 24576),
            "v"(pb + 32768), "v"(pb + 40960), "v"(pb + 49152),
            "v"(pb + 57344)
          : "memory");
      const unsigned bad =
          (d0[1] ^ tg) | (d0[3] ^ tg) | (d1[1] ^ tg) | (d1[3] ^ tg) |
          (d2[1] ^ tg) | (d2[3] ^ tg) | (d3[1] ^ tg) | (d3[3] ^ tg) |
          (d4[1] ^ tg) | (d4[3] ^ tg) | (d5[1] ^ tg) | (d5[3] ^ tg) |
          (d6[1] ^ tg) | (d6[3] ^ tg) | (d7[1] ^ tg) | (d7[3] ^ tg) |
          (d8[1] ^ tg) | (d8[3] ^ tg) | (d9[1] ^ tg) | (d9[3] ^ tg) |
          (d10[1] ^ tg) | (d10[3] ^ tg) | (d11[1] ^ tg) | (d11[3] ^ tg) |
          (d12[1] ^ tg) | (d12[3] ^ tg) | (d13[1] ^ tg) | (d13[3] ^ tg) |
          (d14[1] ^ tg) | (d14[3] ^ tg) | (d15[1] ^ tg) | (d15[3] ^ tg);
      if (bad == 0) break;
    }
    {
      const int u2 = 2 * tid;
#define STW(J, D)                                  \
  {                                                \
    u32x2 w = {D[0], D[2]};                        \
    *(u32x2*)&lds_a[J][u2] = w;                    \
  }
      STW(0, d0) STW(1, d1) STW(2, d2) STW(3, d3) STW(4, d4) STW(5, d5)
      STW(6, d6) STW(7, d7) STW(8, d8) STW(9, d9) STW(10, d10) STW(11, d11)
      STW(12, d12) STW(13, d13) STW(14, d14) STW(15, d15)
#undef STW
    }
    __syncthreads();

    // ---- 2) A-fragments + partial GEMM: 7 gates x 4 kt x 3-term ----
    f32x4 acc[7];
#pragma unroll
    for (int g = 0; g < 7; ++g) acc[g] = (f32x4){0.0f, 0.0f, 0.0f, 0.0f};
    const unsigned int* ap = &lds_a[nl][wave * 128 + kg * 8];
#pragma unroll
    for (int kt = 0; kt < 4; ++kt) {
      const u32x4 x0 = *(const u32x4*)(ap + kt * 32);
      const u32x4 x1 = *(const u32x4*)(ap + kt * 32 + 4);
      s16x8 ah, al;
      unpack(x0, x1, ah, al);
#pragma unroll
      for (int g = 0; g < 7; ++g) {
        acc[g] = mfma_bf16(al, whi[g][kt], acc[g]);
        acc[g] = mfma_bf16(ah, wlo[g][kt], acc[g]);
        acc[g] = mfma_bf16(ah, whi[g][kt], acc[g]);
      }
    }
#pragma unroll
    for (int g = 0; g < 7; ++g)
      *(f32x4*)&pl[g][nl][wave * 16 + kg * 4] = acc[g];
    __syncthreads();

    // ---- 3) reduce + pointwise + publish (all 256 threads) ----
    {
      float gv[7];
#pragma unroll
      for (int m = 0; m < 7; ++m) {
        const float* q = &pl[m][j_loc][b_loc];
        gv[m] = ((q[0] + q[16]) + (q[32] + q[48])) + rb[m];
      }
      const float gi = fsigmoid(gv[0]);
      const float gf = fsigmoid(gv[1]);
      const float gz = ftanh(gv[2]);
      const float go = fsigmoid(gv[3]);
      const float gib = fsigmoid(gv[4]);
      const float gfb = fsigmoid(gv[5]);
      const float gd = fsoftplus(gv[6]);

      const float c = fmaf(gf, c_d, gi * gz);
      c_bar = fmaf(gfb, c_bar, gib * gz);
      c_d = c_bar + (c - c_bar) * fexp2(-gd * dtv * kLog2e);
      const float hd = go * ftanh(c_d);

      // fire-and-forget tagged publish (8B atomic store)
      const unsigned int hh = f2bf(hd);
      const unsigned int hl = f2bf(hd - bf2f((unsigned short)hh));
      u32x2 pub = {hh | (hl << 16), (unsigned int)s};
      st_coh_x2(hdtag + (size_t)((s & 1) * kBH + b_glob * kH + u_pw) * 2,
                pub);

      float* orow = out + ((size_t)b_glob * (kT + 1) + s) * kOutRow;
      __builtin_nontemporal_store(hd, orow + u_pw);
      __builtin_nontemporal_store(go, orow + kH + u_pw);
      __builtin_nontemporal_store(c_bar, orow + 2 * kH + u_pw);
      __builtin_nontemporal_store(c, orow + 3 * kH + u_pw);
      __builtin_nontemporal_store(gd, orow + 4 * kH + u_pw);

      // prefetch next step's rbias/dt (off critical path)
      if (s < kT) {
        const int mk = marks[b_glob * kT + s];
        dtv = dt[b_glob * kT + s];
#pragma unroll
        for (int m = 0; m < 7; ++m)
          rb[m] = emb_part[(size_t)mk * kNC + m * kH + u_pw] +
                  lat_part[(size_t)b_glob * kNC + m * kH + u_pw];
      }
    }
  }
}

}  // namespace

extern "C" void kernel_launch(void* const* d_in, const int* in_sizes, int n_in,
                              void* d_out, int out_size, void* d_ws,
                              size_t ws_size, hipStream_t stream) {
  const int* marks = (const int*)d_in[0];
  const float* ts = (const float*)d_in[1];
  const float* latent = (const float*)d_in[2];
  const float* emb = (const float*)d_in[3];
  const float* Wc = (const float*)d_in[4];
  const float* bc = (const float*)d_in[5];
  const float* Wi = (const float*)d_in[6];
  const float* bi = (const float*)d_in[7];
  float* out = (float*)d_out;

  char* ws = (char*)d_ws;
  float* emb_part = (float*)(ws + 0);                 // 1,835,008 B
  float* lat_part = (float*)(ws + 1835008);           //   458,752 B
  float* dt       = (float*)(ws + 2293760);           //    65,536 B
  float* cd0      = (float*)(ws + 2359296);           //    65,536 B
  float* cb0      = (float*)(ws + 2424832);           //    65,536 B
  unsigned int* hdtag = (unsigned int*)(ws + 2490368); //  262,144 B

  hawkes_setup<<<286, 256, 0, stream>>>(ts, latent, emb, Wc, bc, Wi, bi, out,
                                        emb_part, lat_part, dt, cd0, cb0,
                                        hdtag);
  hawkes_seq<<<64, 256, 0, stream>>>(marks, Wc, out, emb_part, lat_part, dt,
                                     cd0, cb0, hdtag);
}